// Round 10
// baseline (250.440 us; speedup 1.0000x reference)
//
#include <hip/hip_runtime.h>

#define LOG2E 1.4426950408889634f

typedef __bf16 bf16x8 __attribute__((ext_vector_type(8)));
typedef float f32x4 __attribute__((ext_vector_type(4)));

__device__ __forceinline__ unsigned short bfb(__bf16 b){
  union { __bf16 b; unsigned short u; } z; z.b = b; return z.u;
}
__device__ __forceinline__ void split8(const float* __restrict__ p, bf16x8& hi, bf16x8& lo){
  #pragma unroll
  for (int j = 0; j < 8; j++){
    float f = p[j];
    __bf16 h = (__bf16)f;
    hi[j] = h;
    lo[j] = (__bf16)(f - (float)h);
  }
}

// ---------------- prep (merged): W2 fold+split, Wv/Wo split, biases, av2 ----------------
__global__ __launch_bounds__(256) void prep_all(
    const float* __restrict__ Wq, const float* __restrict__ Aq,
    const float* __restrict__ Wk, const float* __restrict__ Ak,
    const float* __restrict__ bq, const float* __restrict__ bk,
    const float* __restrict__ av,
    const float* __restrict__ Wv, const float* __restrict__ Wo,
    unsigned short* __restrict__ W2q_hi, unsigned short* __restrict__ W2q_lo,
    unsigned short* __restrict__ W2k_hi, unsigned short* __restrict__ W2k_lo,
    unsigned short* __restrict__ Wvh, unsigned short* __restrict__ Wvl,
    unsigned short* __restrict__ Woh, unsigned short* __restrict__ Wol,
    float* __restrict__ b2q, float* __restrict__ b2k, float* __restrict__ av2g){
  if (blockIdx.x >= 1024){
    if (blockIdx.x == 1280){
      if (blockIdx.y == 0){
        #pragma unroll
        for (int rep = 0; rep < 2; rep++){
          int n = rep * 256 + threadIdx.x;
          int h = n >> 6, e = n & 63;
          float aq = 0.f, ak = 0.f;
          for (int c = 0; c < 64; c++){
            aq += Aq[e*64 + c] * bq[h*64 + c];
            ak += Ak[e*64 + c] * bk[h*64 + c];
          }
          b2q[n] = aq * (2.f * LOG2E);
          b2k[n] = ak * (2.f * LOG2E);
        }
      } else {
        if (threadIdx.x < 64) av2g[threadIdx.x] = -2.f * LOG2E * av[threadIdx.x];
      }
      return;
    }
    const float* src = blockIdx.y ? Wo : Wv;
    unsigned short* hi = blockIdx.y ? Woh : Wvh;
    unsigned short* lo = blockIdx.y ? Wol : Wvl;
    int base = ((blockIdx.x - 1024) * 256 + threadIdx.x) * 4;
    float4 v = *(const float4*)(src + base);
    ushort4 h, l;
    float f; __bf16 hb;
    f = v.x; hb = (__bf16)f; h.x = bfb(hb); l.x = bfb((__bf16)(f - (float)hb));
    f = v.y; hb = (__bf16)f; h.y = bfb(hb); l.y = bfb((__bf16)(f - (float)hb));
    f = v.z; hb = (__bf16)f; h.z = bfb(hb); l.z = bfb((__bf16)(f - (float)hb));
    f = v.w; hb = (__bf16)f; h.w = bfb(hb); l.w = bfb((__bf16)(f - (float)hb));
    *(ushort4*)(hi + base) = h;
    *(ushort4*)(lo + base) = l;
    return;
  }
  const float* W  = blockIdx.y ? Wk : Wq;
  const float* Am = blockIdx.y ? Ak : Aq;
  unsigned short* WH = blockIdx.y ? W2k_hi : W2q_hi;
  unsigned short* WL = blockIdx.y ? W2k_lo : W2q_lo;
  int idx = blockIdx.x * 256 + threadIdx.x;
  int n = idx >> 9, k = idx & 511;
  int h = n >> 6, e = n & 63;
  float acc = 0.f;
  #pragma unroll 8
  for (int c = 0; c < 64; c++)
    acc += Am[e*64 + c] * W[(h*64 + c)*512 + k];
  float v = acc * (2.f * LOG2E);
  __bf16 hb = (__bf16)v;
  WH[n*512 + k] = bfb(hb);
  WL[n*512 + k] = bfb((__bf16)(v - (float)hb));
}

// ---------------- MFMA GEMM: C[1024][512] = A(fp32) * B^T(pre-split hi/lo) + bias ----------
struct GemmBatch {
  const float* Af;
  const unsigned short *Bh, *Bl;
  const float* bias;
  float* Cf;
  int transposed;                  // 1: qpT layout ((b*8+h)*64+dk)*512 + i
};
struct GemmArgs { GemmBatch g[3]; };

__global__ __launch_bounds__(256) void gemm_nk(GemmArgs ga){
  GemmBatch gb = ga.g[blockIdx.z];
  const int lane = threadIdx.x & 63;
  const int w    = threadIdx.x >> 6;
  const int l15  = lane & 15, quad = lane >> 4;
  const int m  = blockIdx.x * 64 + w * 16 + l15;
  const int nb = blockIdx.y * 64 + l15;
  const float* Arow = gb.Af + (size_t)m * 512;
  f32x4 ac0 = {0.f,0.f,0.f,0.f}, ac1 = ac0, ac2 = ac0, ac3 = ac0;

  #pragma unroll 2
  for (int ks = 0; ks < 16; ks++){
    int ko = ks * 32 + quad * 8;
    bf16x8 ah, al;
    split8(Arow + ko, ah, al);
    #pragma unroll
    for (int t = 0; t < 4; t++){
      bf16x8 bh = *(const bf16x8*)(gb.Bh + (size_t)(nb + t*16) * 512 + ko);
      bf16x8 bl = *(const bf16x8*)(gb.Bl + (size_t)(nb + t*16) * 512 + ko);
      f32x4& ac = (t==0)?ac0:(t==1)?ac1:(t==2)?ac2:ac3;
      ac = __builtin_amdgcn_mfma_f32_16x16x32_bf16(ah, bh, ac, 0, 0, 0);
      ac = __builtin_amdgcn_mfma_f32_16x16x32_bf16(al, bh, ac, 0, 0, 0);
      ac = __builtin_amdgcn_mfma_f32_16x16x32_bf16(ah, bl, ac, 0, 0, 0);
    }
  }

  const int mrow = blockIdx.x * 64 + w * 16 + quad * 4;
  #pragma unroll
  for (int t = 0; t < 4; t++){
    f32x4 v = (t==0)?ac0:(t==1)?ac1:(t==2)?ac2:ac3;
    int n = blockIdx.y * 64 + t * 16 + l15;
    float bs = gb.bias[n];
    #pragma unroll
    for (int r = 0; r < 4; r++){
      float val = v[r] + bs;
      int m2 = mrow + r;
      if (gb.transposed){
        gb.Cf[(size_t)(((m2 >> 9) * 8 + (n >> 6)) * 64 + (n & 63)) * 512 + (m2 & 511)] = val;
      } else {
        gb.Cf[(size_t)m2 * 512 + n] = val;
      }
    }
  }
}

// ---------------- fused additive-attention core (register-direct K, global V, 1 barrier) --
// grid (32,16): x = 16-row block, y = bh. 512 thr = 8 waves.
// Score: wave w owns rows 2w,2w+1; lane owns j = 2*lane, 2*lane+1 — K rows read DIRECT
// from global into registers (no LDS). P round-trips through dbuf LDS (layout change
// for MFMA). PV: A = P (m=row, k=j), B = V read DIRECT from global (coalesced per quad).
__global__ __launch_bounds__(512, 4) void attn_kernel(
    const float* __restrict__ qpT, const float* __restrict__ kp,
    const float* __restrict__ Vv, const float* __restrict__ av2g,
    float* __restrict__ Oh){
  __shared__ unsigned short pcb[2][2 * 16 * 136];   // dbuf x [hi/lo][row][136]
  __shared__ float cmb[1024];
  __shared__ float dn[16];

  const int tid = threadIdx.x, lane = tid & 63, w = tid >> 6;
  const int l15 = lane & 15, quad = lane >> 4;
  const int bh = blockIdx.y;
  const int i0 = blockIdx.x * 16;
  const size_t kbase = (size_t)(bh >> 3) * 512 * 512 + (size_t)(bh & 7) * 64;
  const int r0 = __builtin_amdgcn_readfirstlane(2 * w);    // rows 2w, 2w+1
  const size_t qbase = (size_t)bh * 64 * 512 + i0 + r0;
  const int ntile = w & 3, khalf = w >> 2;
  const int dcol = ntile * 16 + l15;

  float den0 = 0.f, den1 = 0.f;
  f32x4 Cacc = {0.f, 0.f, 0.f, 0.f};

  for (int c = 0; c < 4; c++){
    // ---- score: K rows 2*lane, 2*lane+1 direct from global, 16-d groups ----
    const float* rowA = kp + kbase + (size_t)(c*128 + 2*lane) * 512;
    const float* rowB = rowA + 512;
    float s00 = 0.f, s01 = 0.f, s10 = 0.f, s11 = 0.f;
    #pragma unroll
    for (int g = 0; g < 4; g++){
      f32x4 A0 = *(const f32x4*)(rowA + g*16);
      f32x4 A1 = *(const f32x4*)(rowA + g*16 + 4);
      f32x4 A2 = *(const f32x4*)(rowA + g*16 + 8);
      f32x4 A3 = *(const f32x4*)(rowA + g*16 + 12);
      f32x4 B0 = *(const f32x4*)(rowB + g*16);
      f32x4 B1 = *(const f32x4*)(rowB + g*16 + 4);
      f32x4 B2 = *(const f32x4*)(rowB + g*16 + 8);
      f32x4 B3 = *(const f32x4*)(rowB + g*16 + 12);
      #pragma unroll
      for (int t = 0; t < 4; t++){
        f32x4 Av = (t==0)?A0:(t==1)?A1:(t==2)?A2:A3;
        f32x4 Bv = (t==0)?B0:(t==1)?B1:(t==2)?B2:B3;
        #pragma unroll
        for (int u = 0; u < 4; u++){
          int d = g*16 + t*4 + u;
          float2 qv = *(const float2*)(qpT + qbase + (size_t)d * 512);  // wave-uniform
          float a2 = av2g[d];                                           // wave-uniform
          float kx = Av[u], ky = Bv[u];
          s00 += a2 * __builtin_amdgcn_rcpf(1.f + __builtin_amdgcn_exp2f(qv.x + kx));
          s01 += a2 * __builtin_amdgcn_rcpf(1.f + __builtin_amdgcn_exp2f(qv.x + ky));
          s10 += a2 * __builtin_amdgcn_rcpf(1.f + __builtin_amdgcn_exp2f(qv.y + kx));
          s11 += a2 * __builtin_amdgcn_rcpf(1.f + __builtin_amdgcn_exp2f(qv.y + ky));
        }
      }
    }
    float e00 = __builtin_amdgcn_exp2f(s00);
    float e01 = __builtin_amdgcn_exp2f(s01);
    float e10 = __builtin_amdgcn_exp2f(s10);
    float e11 = __builtin_amdgcn_exp2f(s11);
    den0 += e00 + e01; den1 += e10 + e11;
    { // publish P hi/lo into current dbuf
      unsigned short* pc = pcb[c & 1];
      __bf16 h00 = (__bf16)e00, h01 = (__bf16)e01, h10 = (__bf16)e10, h11 = (__bf16)e11;
      ushort2 hi0 = { bfb(h00), bfb(h01) };
      ushort2 hi1 = { bfb(h10), bfb(h11) };
      ushort2 lo0 = { bfb((__bf16)(e00 - (float)h00)), bfb((__bf16)(e01 - (float)h01)) };
      ushort2 lo1 = { bfb((__bf16)(e10 - (float)h10)), bfb((__bf16)(e11 - (float)h11)) };
      *(ushort2*)&pc[(0*16 + r0    ) * 136 + 2*lane] = hi0;
      *(ushort2*)&pc[(0*16 + r0 + 1) * 136 + 2*lane] = hi1;
      *(ushort2*)&pc[(1*16 + r0    ) * 136 + 2*lane] = lo0;
      *(ushort2*)&pc[(1*16 + r0 + 1) * 136 + 2*lane] = lo1;
    }
    __syncthreads();   // P_c visible; PV_{c-1} finished before publish in program order
    { // PV MFMA: A = P rows, B = V[j][dcol] direct from global
      const unsigned short* pc = pcb[c & 1];
      #pragma unroll
      for (int kk2 = 0; kk2 < 2; kk2++){
        int jb = (khalf * 2 + kk2) * 32 + quad * 8;
        bf16x8 ph = *(const bf16x8*)&pc[(0*16 + l15) * 136 + jb];
        bf16x8 pl = *(const bf16x8*)&pc[(1*16 + l15) * 136 + jb];
        const float* vptr = Vv + kbase + (size_t)(c*128 + jb) * 512 + dcol;
        bf16x8 vh, vl;
        #pragma unroll
        for (int j = 0; j < 8; j++){
          float f = vptr[(size_t)j * 512];
          __bf16 h = (__bf16)f;
          vh[j] = h; vl[j] = (__bf16)(f - (float)h);
        }
        Cacc = __builtin_amdgcn_mfma_f32_16x16x32_bf16(ph, vh, Cacc, 0, 0, 0);
        Cacc = __builtin_amdgcn_mfma_f32_16x16x32_bf16(pl, vh, Cacc, 0, 0, 0);
        Cacc = __builtin_amdgcn_mfma_f32_16x16x32_bf16(ph, vl, Cacc, 0, 0, 0);
      }
    }
  }

  // den reduction: wave w owns rows 2w, 2w+1
  #pragma unroll
  for (int off = 1; off < 64; off <<= 1){
    den0 += __shfl_xor(den0, off, 64);
    den1 += __shfl_xor(den1, off, 64);
  }
  if (lane == 0){ dn[r0] = den0; dn[r0 + 1] = den1; }
  __syncthreads();
  if (w >= 4){
    #pragma unroll
    for (int r = 0; r < 4; r++) cmb[(w - 4) * 256 + lane * 4 + r] = Cacc[r];
  }
  __syncthreads();
  if (w < 4){
    #pragma unroll
    for (int r = 0; r < 4; r++){
      float cv = Cacc[r] + cmb[w * 256 + lane * 4 + r];
      int row = quad * 4 + r;
      Oh[kbase + (size_t)(i0 + row) * 512 + dcol] = cv / dn[row];   // ntile == w for w<4
    }
  }
}

// ---------------- launch ----------------
extern "C" void kernel_launch(void* const* d_in, const int* in_sizes, int n_in,
                              void* d_out, int out_size, void* d_ws, size_t ws_size,
                              hipStream_t stream){
  const float* q_in = (const float*)d_in[0];
  const float* k_in = (const float*)d_in[1];
  const float* v_in = (const float*)d_in[2];
  const float* Wq_  = (const float*)d_in[3];
  const float* bq_  = (const float*)d_in[4];
  const float* Wk_  = (const float*)d_in[5];
  const float* bk_  = (const float*)d_in[6];
  const float* Wv_  = (const float*)d_in[7];
  const float* bv_  = (const float*)d_in[8];
  const float* Wo_  = (const float*)d_in[9];
  const float* bo_  = (const float*)d_in[10];
  const float* Aq_  = (const float*)d_in[11];
  const float* Ak_  = (const float*)d_in[12];
  const float* av_  = (const float*)d_in[13];

  char* ws = (char*)d_ws;
  unsigned short* W2q_hi = (unsigned short*)(ws + 0);
  unsigned short* W2q_lo = (unsigned short*)(ws + 524288);
  unsigned short* W2k_hi = (unsigned short*)(ws + 1048576);
  unsigned short* W2k_lo = (unsigned short*)(ws + 1572864);
  float* Oh = (float*)(ws + 0);
  unsigned short* Wvh = (unsigned short*)(ws + 2097152);
  unsigned short* Wvl = (unsigned short*)(ws + 2621440);
  unsigned short* Woh = (unsigned short*)(ws + 3145728);
  unsigned short* Wol = (unsigned short*)(ws + 3670016);
  float* b2q  = (float*)(ws + 4194304);
  float* b2k  = (float*)(ws + 4196352);
  float* av2g = (float*)(ws + 4198400);
  float* qpT  = (float*)(ws + 4198656);
  float* kp   = (float*)(ws + 6295808);
  float* Vw   = (float*)(ws + 8392960);

  prep_all<<<dim3(1281, 2, 1), 256, 0, stream>>>(Wq_, Aq_, Wk_, Ak_, bq_, bk_, av_,
                                                 Wv_, Wo_,
                                                 W2q_hi, W2q_lo, W2k_hi, W2k_lo,
                                                 Wvh, Wvl, Woh, Wol,
                                                 b2q, b2k, av2g);

  GemmArgs ga;
  ga.g[0] = { q_in, W2q_hi, W2q_lo, b2q, qpT, 1 };
  ga.g[1] = { k_in, W2k_hi, W2k_lo, b2k, kp,  0 };
  ga.g[2] = { v_in, Wvh,    Wvl,    bv_, Vw,  0 };
  gemm_nk<<<dim3(16, 8, 3), 256, 0, stream>>>(ga);

  attn_kernel<<<dim3(32, 16, 1), 512, 0, stream>>>(qpT, kp, Vw, av2g, Oh);

  GemmArgs go;
  go.g[0] = { Oh, Woh, Wol, bo_, (float*)d_out, 0 };
  go.g[1] = go.g[0];
  go.g[2] = go.g[0];
  gemm_nk<<<dim3(16, 8, 1), 256, 0, stream>>>(go);
}

// Round 11
// 188.438 us; speedup vs baseline: 1.3290x; 1.3290x over previous
//
#include <hip/hip_runtime.h>

#define LOG2E 1.4426950408889634f

typedef __bf16 bf16x8 __attribute__((ext_vector_type(8)));
typedef float f32x4 __attribute__((ext_vector_type(4)));

__device__ __forceinline__ unsigned short bfb(__bf16 b){
  union { __bf16 b; unsigned short u; } z; z.b = b; return z.u;
}
__device__ __forceinline__ void split8(const float* p, bf16x8& hi, bf16x8& lo){
  #pragma unroll
  for (int j = 0; j < 8; j++){
    float f = p[j];
    __bf16 h = (__bf16)f;
    hi[j] = h;
    lo[j] = (__bf16)(f - (float)h);
  }
}

// Packed-B layout: element (n,k) hi/lo -> ((nt*16+ks)*2+hl)*512 + lane*8 + j
//   nt=n>>4, ln=n&15, ks=k>>5, q=(k&31)>>3, j=k&7, lane=q*16+ln
// GEMM reads one wave-contiguous 1KB line per (nt,ks,hl).

// ---------------- prep: W2 fold + packed split, Wv/Wo packed split, biases, av2 ----------
__global__ __launch_bounds__(256) void prep_all(
    const float* __restrict__ Wq, const float* __restrict__ Aq,
    const float* __restrict__ Wk, const float* __restrict__ Ak,
    const float* __restrict__ bq, const float* __restrict__ bk,
    const float* __restrict__ av,
    const float* __restrict__ Wv, const float* __restrict__ Wo,
    unsigned short* __restrict__ W2qp, unsigned short* __restrict__ W2kp,
    unsigned short* __restrict__ Wvp,  unsigned short* __restrict__ Wop,
    float* __restrict__ b2q, float* __restrict__ b2k, float* __restrict__ av2g){
  if (blockIdx.x >= 1024){
    if (blockIdx.x == 1280){
      if (blockIdx.y == 0){
        #pragma unroll
        for (int rep = 0; rep < 2; rep++){
          int n = rep * 256 + threadIdx.x;
          int h = n >> 6, e = n & 63;
          float aq = 0.f, ak = 0.f;
          for (int c = 0; c < 64; c++){
            aq += Aq[e*64 + c] * bq[h*64 + c];
            ak += Ak[e*64 + c] * bk[h*64 + c];
          }
          b2q[n] = aq * (2.f * LOG2E);
          b2k[n] = ak * (2.f * LOG2E);
        }
      } else {
        if (threadIdx.x < 64) av2g[threadIdx.x] = -2.f * LOG2E * av[threadIdx.x];
      }
      return;
    }
    // packed split of Wv / Wo (4 consecutive k of one row per thread)
    const float* src = blockIdx.y ? Wo : Wv;
    unsigned short* dst = blockIdx.y ? Wop : Wvp;
    int base = ((blockIdx.x - 1024) * 256 + threadIdx.x) * 4;
    int n = base >> 9, k0 = base & 511;
    float4 v = *(const float4*)(src + base);
    ushort4 h, l;
    float f; __bf16 hb;
    f = v.x; hb = (__bf16)f; h.x = bfb(hb); l.x = bfb((__bf16)(f - (float)hb));
    f = v.y; hb = (__bf16)f; h.y = bfb(hb); l.y = bfb((__bf16)(f - (float)hb));
    f = v.z; hb = (__bf16)f; h.z = bfb(hb); l.z = bfb((__bf16)(f - (float)hb));
    f = v.w; hb = (__bf16)f; h.w = bfb(hb); l.w = bfb((__bf16)(f - (float)hb));
    int nt = n >> 4, ln = n & 15;
    int ks = k0 >> 5, q = (k0 & 31) >> 3, j0 = k0 & 7;     // j0 in {0,4}
    size_t off = (size_t)((nt*16 + ks) * 2) * 512 + (q*16 + ln) * 8 + j0;
    *(ushort4*)(dst + off)       = h;
    *(ushort4*)(dst + off + 512) = l;
    return;
  }
  // W2 fold + packed split
  const float* W  = blockIdx.y ? Wk : Wq;
  const float* Am = blockIdx.y ? Ak : Aq;
  unsigned short* dst = blockIdx.y ? W2kp : W2qp;
  int idx = blockIdx.x * 256 + threadIdx.x;
  int n = idx >> 9, k = idx & 511;
  int h = n >> 6, e = n & 63;
  float acc = 0.f;
  #pragma unroll 8
  for (int c = 0; c < 64; c++)
    acc += Am[e*64 + c] * W[(h*64 + c)*512 + k];
  float v = acc * (2.f * LOG2E);
  __bf16 hb = (__bf16)v;
  int nt = n >> 4, ln = n & 15;
  int ks = k >> 5, q = (k & 31) >> 3, j = k & 7;
  size_t off = (size_t)((nt*16 + ks) * 2) * 512 + (q*16 + ln) * 8 + j;
  dst[off]       = bfb(hb);
  dst[off + 512] = bfb((__bf16)(v - (float)hb));
}

// ---------------- MFMA GEMM: LDS-staged A (fp32), packed-fragment B ----------------
struct GemmBatch {
  const float* Af;               // fp32 A [1024][512]
  const unsigned short* Bp;      // packed hi/lo B
  const float* bias;
  float* Cf;
  int transposed;                // 1: qpT layout ((b*8+h)*64+dk)*512 + i
};
struct GemmArgs { GemmBatch g[3]; };

__global__ __launch_bounds__(256) void gemm_nk(GemmArgs ga){
  GemmBatch gb = ga.g[blockIdx.z];
  __shared__ float As[64 * 68];            // 64 m-rows x 64 k, stride 68
  const int tid = threadIdx.x, lane = tid & 63, w = tid >> 6;
  const int l15 = lane & 15, quad = lane >> 4;
  const int m0  = blockIdx.x * 64;
  const int nt0 = blockIdx.y * 4;
  f32x4 ac0 = {0.f,0.f,0.f,0.f}, ac1 = ac0, ac2 = ac0, ac3 = ac0;

  const int sr = tid >> 2;                  // staging row 0..63
  const int sc = (tid & 3) * 16;            // staging col base
  const float* srcA = gb.Af + (size_t)(m0 + sr) * 512 + sc;
  float* dstA = &As[sr * 68 + sc];

  for (int kc = 0; kc < 8; kc++){
    __syncthreads();
    #pragma unroll
    for (int i = 0; i < 4; i++)
      *(f32x4*)(dstA + i*4) = *(const f32x4*)(srcA + kc*64 + i*4);
    __syncthreads();
    #pragma unroll
    for (int s = 0; s < 2; s++){
      int ks = kc * 2 + s;
      bf16x8 ah, al;
      split8(&As[(w*16 + l15) * 68 + s*32 + quad*8], ah, al);
      #pragma unroll
      for (int t = 0; t < 4; t++){
        const unsigned short* bp = gb.Bp + (size_t)(((nt0 + t)*16 + ks) * 2) * 512 + lane*8;
        bf16x8 bh = *(const bf16x8*)bp;
        bf16x8 bl = *(const bf16x8*)(bp + 512);
        f32x4& ac = (t==0)?ac0:(t==1)?ac1:(t==2)?ac2:ac3;
        ac = __builtin_amdgcn_mfma_f32_16x16x32_bf16(ah, bh, ac, 0, 0, 0);
        ac = __builtin_amdgcn_mfma_f32_16x16x32_bf16(al, bh, ac, 0, 0, 0);
        ac = __builtin_amdgcn_mfma_f32_16x16x32_bf16(ah, bl, ac, 0, 0, 0);
      }
    }
  }

  const int mrow = m0 + w * 16 + quad * 4;   // C/D: col=l15, row=quad*4+reg
  #pragma unroll
  for (int t = 0; t < 4; t++){
    f32x4 v = (t==0)?ac0:(t==1)?ac1:(t==2)?ac2:ac3;
    int n = nt0 * 16 + t * 16 + l15;
    float bs = gb.bias[n];
    #pragma unroll
    for (int r = 0; r < 4; r++){
      float val = v[r] + bs;
      int m2 = mrow + r;
      if (gb.transposed){
        gb.Cf[(size_t)(((m2 >> 9) * 8 + (n >> 6)) * 64 + (n & 63)) * 512 + (m2 & 511)] = val;
      } else {
        gb.Cf[(size_t)m2 * 512 + n] = val;
      }
    }
  }
}

// ---------------- fused additive-attention core (R8: MFMA PV, pipelined 2-barrier) -------
__global__ __launch_bounds__(512, 4) void attn_kernel(
    const float* __restrict__ qpT, const float* __restrict__ kp,
    const float* __restrict__ Vv, const float* __restrict__ av2g,
    float* __restrict__ Oh){
  __shared__ float bufA[64 * 130];
  __shared__ float bufB[64 * 130];
  __shared__ unsigned short pcb[2 * 16 * 136];
  __shared__ float dn[16];
  float* cmb = bufA;

  const int tid = threadIdx.x, lane = tid & 63, w = tid >> 6;
  const int l15 = lane & 15, quad = lane >> 4;
  const int bh = blockIdx.y;
  const int i0 = blockIdx.x * 16;
  const size_t kbase = (size_t)(bh >> 3) * 512 * 512 + (size_t)(bh & 7) * 64;
  const int r0 = __builtin_amdgcn_readfirstlane(2 * w);
  const size_t qbase = (size_t)bh * 64 * 512 + i0 + r0;
  const int ntile = w & 3, khalf = w >> 2;

  float den0 = 0.f, den1 = 0.f;
  f32x4 Cacc = {0.f, 0.f, 0.f, 0.f};

  { // init: stage K_0 -> bufA
    #pragma unroll
    for (int m = 0; m < 8; m++){
      int i = w + 8 * m;
      float a = kp[kbase + (size_t)(2*i    ) * 512 + lane];
      float b = kp[kbase + (size_t)(2*i + 1) * 512 + lane];
      *(float2*)&bufA[lane * 130 + 2*i] = make_float2(a, b);
    }
  }
  __syncthreads();

  for (int c = 0; c < 4; c++){
    // ---- X: V_c global->regs, score from bufA, publish P, V->bufB ----
    float va[8], vb[8];
    #pragma unroll
    for (int m = 0; m < 8; m++){
      int i = w + 8 * m;
      va[m] = Vv[kbase + (size_t)(c*128 + 2*i    ) * 512 + lane];
      vb[m] = Vv[kbase + (size_t)(c*128 + 2*i + 1) * 512 + lane];
    }
    float s00 = 0.f, s01 = 0.f, s10 = 0.f, s11 = 0.f;
    #pragma unroll 4
    for (int d = 0; d < 64; d++){
      float2 qv = *(const float2*)(qpT + qbase + (size_t)d * 512);  // wave-uniform
      float a2 = av2g[d];                                           // wave-uniform
      float2 kk = *(const float2*)&bufA[d * 130 + 2 * lane];
      s00 += a2 * __builtin_amdgcn_rcpf(1.f + __builtin_amdgcn_exp2f(qv.x + kk.x));
      s01 += a2 * __builtin_amdgcn_rcpf(1.f + __builtin_amdgcn_exp2f(qv.x + kk.y));
      s10 += a2 * __builtin_amdgcn_rcpf(1.f + __builtin_amdgcn_exp2f(qv.y + kk.x));
      s11 += a2 * __builtin_amdgcn_rcpf(1.f + __builtin_amdgcn_exp2f(qv.y + kk.y));
    }
    float e00 = __builtin_amdgcn_exp2f(s00);
    float e01 = __builtin_amdgcn_exp2f(s01);
    float e10 = __builtin_amdgcn_exp2f(s10);
    float e11 = __builtin_amdgcn_exp2f(s11);
    den0 += e00 + e01; den1 += e10 + e11;
    {
      __bf16 h00 = (__bf16)e00, h01 = (__bf16)e01, h10 = (__bf16)e10, h11 = (__bf16)e11;
      ushort2 hi0 = { bfb(h00), bfb(h01) };
      ushort2 hi1 = { bfb(h10), bfb(h11) };
      ushort2 lo0 = { bfb((__bf16)(e00 - (float)h00)), bfb((__bf16)(e01 - (float)h01)) };
      ushort2 lo1 = { bfb((__bf16)(e10 - (float)h10)), bfb((__bf16)(e11 - (float)h11)) };
      *(ushort2*)&pcb[(0*16 + r0    ) * 136 + 2*lane] = hi0;
      *(ushort2*)&pcb[(0*16 + r0 + 1) * 136 + 2*lane] = hi1;
      *(ushort2*)&pcb[(1*16 + r0    ) * 136 + 2*lane] = lo0;
      *(ushort2*)&pcb[(1*16 + r0 + 1) * 136 + 2*lane] = lo1;
    }
    #pragma unroll
    for (int m = 0; m < 8; m++){
      int i = w + 8 * m;
      *(float2*)&bufB[lane * 130 + 2*i] = make_float2(va[m], vb[m]);
    }
    __syncthreads();

    // ---- Y: K_{c+1} global->regs, PV MFMA from bufB/pcb, K->bufA ----
    float ka[8], kb[8];
    if (c < 3){
      #pragma unroll
      for (int m = 0; m < 8; m++){
        int i = w + 8 * m;
        ka[m] = kp[kbase + (size_t)((c+1)*128 + 2*i    ) * 512 + lane];
        kb[m] = kp[kbase + (size_t)((c+1)*128 + 2*i + 1) * 512 + lane];
      }
    }
    #pragma unroll
    for (int kk2 = 0; kk2 < 2; kk2++){
      int k0 = (khalf * 2 + kk2) * 32 + quad * 8;
      bf16x8 ph = *(const bf16x8*)&pcb[(0*16 + l15) * 136 + k0];
      bf16x8 pl = *(const bf16x8*)&pcb[(1*16 + l15) * 136 + k0];
      const float* vp = &bufB[(ntile*16 + l15) * 130 + k0];
      bf16x8 vh, vl;
      #pragma unroll
      for (int j = 0; j < 8; j++){
        float f = vp[j];
        __bf16 h = (__bf16)f;
        vh[j] = h; vl[j] = (__bf16)(f - (float)h);
      }
      Cacc = __builtin_amdgcn_mfma_f32_16x16x32_bf16(ph, vh, Cacc, 0, 0, 0);
      Cacc = __builtin_amdgcn_mfma_f32_16x16x32_bf16(pl, vh, Cacc, 0, 0, 0);
      Cacc = __builtin_amdgcn_mfma_f32_16x16x32_bf16(ph, vl, Cacc, 0, 0, 0);
    }
    if (c < 3){
      #pragma unroll
      for (int m = 0; m < 8; m++){
        int i = w + 8 * m;
        *(float2*)&bufA[lane * 130 + 2*i] = make_float2(ka[m], kb[m]);
      }
    }
    __syncthreads();
  }

  #pragma unroll
  for (int off = 1; off < 64; off <<= 1){
    den0 += __shfl_xor(den0, off, 64);
    den1 += __shfl_xor(den1, off, 64);
  }
  if (lane == 0){ dn[r0] = den0; dn[r0 + 1] = den1; }
  __syncthreads();
  if (w >= 4){
    #pragma unroll
    for (int r = 0; r < 4; r++) cmb[(w - 4) * 256 + lane * 4 + r] = Cacc[r];
  }
  __syncthreads();
  if (w < 4){
    #pragma unroll
    for (int r = 0; r < 4; r++){
      float cv = Cacc[r] + cmb[w * 256 + lane * 4 + r];
      int row = quad * 4 + r;
      int d = ntile * 16 + l15;
      Oh[kbase + (size_t)(i0 + row) * 512 + d] = cv / dn[row];
    }
  }
}

// ---------------- launch ----------------
extern "C" void kernel_launch(void* const* d_in, const int* in_sizes, int n_in,
                              void* d_out, int out_size, void* d_ws, size_t ws_size,
                              hipStream_t stream){
  const float* q_in = (const float*)d_in[0];
  const float* k_in = (const float*)d_in[1];
  const float* v_in = (const float*)d_in[2];
  const float* Wq_  = (const float*)d_in[3];
  const float* bq_  = (const float*)d_in[4];
  const float* Wk_  = (const float*)d_in[5];
  const float* bk_  = (const float*)d_in[6];
  const float* Wv_  = (const float*)d_in[7];
  const float* bv_  = (const float*)d_in[8];
  const float* Wo_  = (const float*)d_in[9];
  const float* bo_  = (const float*)d_in[10];
  const float* Aq_  = (const float*)d_in[11];
  const float* Ak_  = (const float*)d_in[12];
  const float* av_  = (const float*)d_in[13];

  char* ws = (char*)d_ws;
  unsigned short* W2qp = (unsigned short*)(ws + 0);          // 1MB packed (dead after proj)
  unsigned short* W2kp = (unsigned short*)(ws + 1048576);    // 1MB
  float* Oh = (float*)(ws + 0);                              // reuse after proj GEMM
  unsigned short* Wvp = (unsigned short*)(ws + 2097152);     // 1MB
  unsigned short* Wop = (unsigned short*)(ws + 3145728);     // 1MB
  float* b2q  = (float*)(ws + 4194304);
  float* b2k  = (float*)(ws + 4196352);
  float* av2g = (float*)(ws + 4198400);
  float* qpT  = (float*)(ws + 4198656);
  float* kp   = (float*)(ws + 6295808);
  float* Vw   = (float*)(ws + 8392960);

  prep_all<<<dim3(1281, 2, 1), 256, 0, stream>>>(Wq_, Aq_, Wk_, Ak_, bq_, bk_, av_,
                                                 Wv_, Wo_,
                                                 W2qp, W2kp, Wvp, Wop,
                                                 b2q, b2k, av2g);

  GemmArgs ga;
  ga.g[0] = { q_in, W2qp, b2q, qpT, 1 };
  ga.g[1] = { k_in, W2kp, b2k, kp,  0 };
  ga.g[2] = { v_in, Wvp,  bv_, Vw,  0 };
  gemm_nk<<<dim3(16, 8, 3), 256, 0, stream>>>(ga);

  attn_kernel<<<dim3(32, 16, 1), 512, 0, stream>>>(qpT, kp, Vw, av2g, Oh);

  GemmArgs go;
  go.g[0] = { Oh, Wop, bo_, (float*)d_out, 0 };
  go.g[1] = go.g[0];
  go.g[2] = go.g[0];
  gemm_nk<<<dim3(16, 8, 1), 256, 0, stream>>>(go);
}

// Round 12
// 169.644 us; speedup vs baseline: 1.4763x; 1.1108x over previous
//
#include <hip/hip_runtime.h>

#define LOG2E 1.4426950408889634f

typedef __bf16 bf16x8 __attribute__((ext_vector_type(8)));
typedef float f32x4 __attribute__((ext_vector_type(4)));

__device__ __forceinline__ unsigned short bfb(__bf16 b){
  union { __bf16 b; unsigned short u; } z; z.b = b; return z.u;
}
__device__ __forceinline__ void split8(const float* p, bf16x8& hi, bf16x8& lo){
  #pragma unroll
  for (int j = 0; j < 8; j++){
    float f = p[j];
    __bf16 h = (__bf16)f;
    hi[j] = h;
    lo[j] = (__bf16)(f - (float)h);
  }
}

// Packed-B layout: element (n,k) hi/lo -> ((nt*16+ks)*2+hl)*512 + lane*8 + j
//   nt=n>>4, ln=n&15, ks=k>>5, q=(k&31)>>3, j=k&7, lane=q*16+ln

// ---------------- prep: W2 fold + packed split, Wv/Wo packed split, biases, av2 ----------
__global__ __launch_bounds__(256) void prep_all(
    const float* __restrict__ Wq, const float* __restrict__ Aq,
    const float* __restrict__ Wk, const float* __restrict__ Ak,
    const float* __restrict__ bq, const float* __restrict__ bk,
    const float* __restrict__ av,
    const float* __restrict__ Wv, const float* __restrict__ Wo,
    unsigned short* __restrict__ W2qp, unsigned short* __restrict__ W2kp,
    unsigned short* __restrict__ Wvp,  unsigned short* __restrict__ Wop,
    float* __restrict__ b2q, float* __restrict__ b2k, float* __restrict__ av2g){
  if (blockIdx.x >= 1024){
    if (blockIdx.x == 1280){
      if (blockIdx.y == 0){
        #pragma unroll
        for (int rep = 0; rep < 2; rep++){
          int n = rep * 256 + threadIdx.x;
          int h = n >> 6, e = n & 63;
          float aq = 0.f, ak = 0.f;
          for (int c = 0; c < 64; c++){
            aq += Aq[e*64 + c] * bq[h*64 + c];
            ak += Ak[e*64 + c] * bk[h*64 + c];
          }
          b2q[n] = aq * (2.f * LOG2E);
          b2k[n] = ak * (2.f * LOG2E);
        }
      } else {
        if (threadIdx.x < 64) av2g[threadIdx.x] = -2.f * LOG2E * av[threadIdx.x];
      }
      return;
    }
    const float* src = blockIdx.y ? Wo : Wv;
    unsigned short* dst = blockIdx.y ? Wop : Wvp;
    int base = ((blockIdx.x - 1024) * 256 + threadIdx.x) * 4;
    int n = base >> 9, k0 = base & 511;
    float4 v = *(const float4*)(src + base);
    ushort4 h, l;
    float f; __bf16 hb;
    f = v.x; hb = (__bf16)f; h.x = bfb(hb); l.x = bfb((__bf16)(f - (float)hb));
    f = v.y; hb = (__bf16)f; h.y = bfb(hb); l.y = bfb((__bf16)(f - (float)hb));
    f = v.z; hb = (__bf16)f; h.z = bfb(hb); l.z = bfb((__bf16)(f - (float)hb));
    f = v.w; hb = (__bf16)f; h.w = bfb(hb); l.w = bfb((__bf16)(f - (float)hb));
    int nt = n >> 4, ln = n & 15;
    int ks = k0 >> 5, q = (k0 & 31) >> 3, j0 = k0 & 7;
    size_t off = (size_t)((nt*16 + ks) * 2) * 512 + (q*16 + ln) * 8 + j0;
    *(ushort4*)(dst + off)       = h;
    *(ushort4*)(dst + off + 512) = l;
    return;
  }
  const float* W  = blockIdx.y ? Wk : Wq;
  const float* Am = blockIdx.y ? Ak : Aq;
  unsigned short* dst = blockIdx.y ? W2kp : W2qp;
  int idx = blockIdx.x * 256 + threadIdx.x;
  int n = idx >> 9, k = idx & 511;
  int h = n >> 6, e = n & 63;
  float acc = 0.f;
  #pragma unroll 8
  for (int c = 0; c < 64; c++)
    acc += Am[e*64 + c] * W[(h*64 + c)*512 + k];
  float v = acc * (2.f * LOG2E);
  __bf16 hb = (__bf16)v;
  int nt = n >> 4, ln = n & 15;
  int ks = k >> 5, q = (k & 31) >> 3, j = k & 7;
  size_t off = (size_t)((nt*16 + ks) * 2) * 512 + (q*16 + ln) * 8 + j;
  dst[off]       = bfb(hb);
  dst[off + 512] = bfb((__bf16)(v - (float)hb));
}

// ---------------- MFMA GEMM: LDS-staged A (fp32), packed-fragment B ----------------
struct GemmBatch {
  const float* Af;
  const unsigned short* Bp;
  const float* bias;
  float* Cf;
  int transposed;                // 1: qpT layout ((b*8+h)*64+dk)*512 + i
  int expout;                    // 1: store exp2(val)
};
struct GemmArgs { GemmBatch g[3]; };

__global__ __launch_bounds__(256) void gemm_nk(GemmArgs ga){
  GemmBatch gb = ga.g[blockIdx.z];
  __shared__ float As[64 * 68];
  const int tid = threadIdx.x, lane = tid & 63, w = tid >> 6;
  const int l15 = lane & 15, quad = lane >> 4;
  const int m0  = blockIdx.x * 64;
  const int nt0 = blockIdx.y * 4;
  f32x4 ac0 = {0.f,0.f,0.f,0.f}, ac1 = ac0, ac2 = ac0, ac3 = ac0;

  const int sr = tid >> 2;
  const int sc = (tid & 3) * 16;
  const float* srcA = gb.Af + (size_t)(m0 + sr) * 512 + sc;
  float* dstA = &As[sr * 68 + sc];

  for (int kc = 0; kc < 8; kc++){
    __syncthreads();
    #pragma unroll
    for (int i = 0; i < 4; i++)
      *(f32x4*)(dstA + i*4) = *(const f32x4*)(srcA + kc*64 + i*4);
    __syncthreads();
    #pragma unroll
    for (int s = 0; s < 2; s++){
      int ks = kc * 2 + s;
      bf16x8 ah, al;
      split8(&As[(w*16 + l15) * 68 + s*32 + quad*8], ah, al);
      #pragma unroll
      for (int t = 0; t < 4; t++){
        const unsigned short* bp = gb.Bp + (size_t)(((nt0 + t)*16 + ks) * 2) * 512 + lane*8;
        bf16x8 bh = *(const bf16x8*)bp;
        bf16x8 bl = *(const bf16x8*)(bp + 512);
        f32x4& ac = (t==0)?ac0:(t==1)?ac1:(t==2)?ac2:ac3;
        ac = __builtin_amdgcn_mfma_f32_16x16x32_bf16(ah, bh, ac, 0, 0, 0);
        ac = __builtin_amdgcn_mfma_f32_16x16x32_bf16(al, bh, ac, 0, 0, 0);
        ac = __builtin_amdgcn_mfma_f32_16x16x32_bf16(ah, bl, ac, 0, 0, 0);
      }
    }
  }

  const int mrow = m0 + w * 16 + quad * 4;
  #pragma unroll
  for (int t = 0; t < 4; t++){
    f32x4 v = (t==0)?ac0:(t==1)?ac1:(t==2)?ac2:ac3;
    int n = nt0 * 16 + t * 16 + l15;
    float bs = gb.bias[n];
    #pragma unroll
    for (int r = 0; r < 4; r++){
      float val = v[r] + bs;
      if (gb.expout) val = __builtin_amdgcn_exp2f(val);
      int m2 = mrow + r;
      if (gb.transposed){
        gb.Cf[(size_t)(((m2 >> 9) * 8 + (n >> 6)) * 64 + (n & 63)) * 512 + (m2 & 511)] = val;
      } else {
        gb.Cf[(size_t)m2 * 512 + n] = val;
      }
    }
  }
}

// ---------------- fused additive-attention core (factored-exp score, MFMA PV) ------------
// EQ = exp2(x~q) (transposed layout), EK = exp2(x~k): sigma = rcp(fma(EQ,EK,1)) — 1 trans.
__global__ __launch_bounds__(512, 4) void attn_kernel(
    const float* __restrict__ eqT, const float* __restrict__ ekp,
    const float* __restrict__ Vv, const float* __restrict__ av2g,
    float* __restrict__ Oh){
  __shared__ float bufA[64 * 130];
  __shared__ float bufB[64 * 130];
  __shared__ unsigned short pcb[2 * 16 * 136];
  __shared__ float dn[16];
  float* cmb = bufA;

  const int tid = threadIdx.x, lane = tid & 63, w = tid >> 6;
  const int l15 = lane & 15, quad = lane >> 4;
  const int bh = blockIdx.y;
  const int i0 = blockIdx.x * 16;
  const size_t kbase = (size_t)(bh >> 3) * 512 * 512 + (size_t)(bh & 7) * 64;
  const int r0 = __builtin_amdgcn_readfirstlane(2 * w);
  const size_t qbase = (size_t)bh * 64 * 512 + i0 + r0;
  const int ntile = w & 3, khalf = w >> 2;

  float den0 = 0.f, den1 = 0.f;
  f32x4 Cacc = {0.f, 0.f, 0.f, 0.f};

  { // init: stage EK_0 -> bufA
    #pragma unroll
    for (int m = 0; m < 8; m++){
      int i = w + 8 * m;
      float a = ekp[kbase + (size_t)(2*i    ) * 512 + lane];
      float b = ekp[kbase + (size_t)(2*i + 1) * 512 + lane];
      *(float2*)&bufA[lane * 130 + 2*i] = make_float2(a, b);
    }
  }
  __syncthreads();

  for (int c = 0; c < 4; c++){
    // ---- X: V_c global->regs, score from bufA, publish P, V->bufB ----
    float va[8], vb[8];
    #pragma unroll
    for (int m = 0; m < 8; m++){
      int i = w + 8 * m;
      va[m] = Vv[kbase + (size_t)(c*128 + 2*i    ) * 512 + lane];
      vb[m] = Vv[kbase + (size_t)(c*128 + 2*i + 1) * 512 + lane];
    }
    float s00 = 0.f, s01 = 0.f, s10 = 0.f, s11 = 0.f;
    #pragma unroll 4
    for (int d = 0; d < 64; d++){
      float2 eq = *(const float2*)(eqT + qbase + (size_t)d * 512);  // wave-uniform
      float a2 = av2g[d];                                           // wave-uniform
      float2 ek = *(const float2*)&bufA[d * 130 + 2 * lane];
      s00 += a2 * __builtin_amdgcn_rcpf(__builtin_fmaf(eq.x, ek.x, 1.f));
      s01 += a2 * __builtin_amdgcn_rcpf(__builtin_fmaf(eq.x, ek.y, 1.f));
      s10 += a2 * __builtin_amdgcn_rcpf(__builtin_fmaf(eq.y, ek.x, 1.f));
      s11 += a2 * __builtin_amdgcn_rcpf(__builtin_fmaf(eq.y, ek.y, 1.f));
    }
    float e00 = __builtin_amdgcn_exp2f(s00);
    float e01 = __builtin_amdgcn_exp2f(s01);
    float e10 = __builtin_amdgcn_exp2f(s10);
    float e11 = __builtin_amdgcn_exp2f(s11);
    den0 += e00 + e01; den1 += e10 + e11;
    {
      __bf16 h00 = (__bf16)e00, h01 = (__bf16)e01, h10 = (__bf16)e10, h11 = (__bf16)e11;
      ushort2 hi0 = { bfb(h00), bfb(h01) };
      ushort2 hi1 = { bfb(h10), bfb(h11) };
      ushort2 lo0 = { bfb((__bf16)(e00 - (float)h00)), bfb((__bf16)(e01 - (float)h01)) };
      ushort2 lo1 = { bfb((__bf16)(e10 - (float)h10)), bfb((__bf16)(e11 - (float)h11)) };
      *(ushort2*)&pcb[(0*16 + r0    ) * 136 + 2*lane] = hi0;
      *(ushort2*)&pcb[(0*16 + r0 + 1) * 136 + 2*lane] = hi1;
      *(ushort2*)&pcb[(1*16 + r0    ) * 136 + 2*lane] = lo0;
      *(ushort2*)&pcb[(1*16 + r0 + 1) * 136 + 2*lane] = lo1;
    }
    #pragma unroll
    for (int m = 0; m < 8; m++){
      int i = w + 8 * m;
      *(float2*)&bufB[lane * 130 + 2*i] = make_float2(va[m], vb[m]);
    }
    __syncthreads();

    // ---- Y: EK_{c+1} global->regs, PV MFMA from bufB/pcb, EK->bufA ----
    float ka[8], kb[8];
    if (c < 3){
      #pragma unroll
      for (int m = 0; m < 8; m++){
        int i = w + 8 * m;
        ka[m] = ekp[kbase + (size_t)((c+1)*128 + 2*i    ) * 512 + lane];
        kb[m] = ekp[kbase + (size_t)((c+1)*128 + 2*i + 1) * 512 + lane];
      }
    }
    #pragma unroll
    for (int kk2 = 0; kk2 < 2; kk2++){
      int k0 = (khalf * 2 + kk2) * 32 + quad * 8;
      bf16x8 ph = *(const bf16x8*)&pcb[(0*16 + l15) * 136 + k0];
      bf16x8 pl = *(const bf16x8*)&pcb[(1*16 + l15) * 136 + k0];
      const float* vp = &bufB[(ntile*16 + l15) * 130 + k0];
      bf16x8 vh, vl;
      #pragma unroll
      for (int j = 0; j < 8; j++){
        float f = vp[j];
        __bf16 h = (__bf16)f;
        vh[j] = h; vl[j] = (__bf16)(f - (float)h);
      }
      Cacc = __builtin_amdgcn_mfma_f32_16x16x32_bf16(ph, vh, Cacc, 0, 0, 0);
      Cacc = __builtin_amdgcn_mfma_f32_16x16x32_bf16(pl, vh, Cacc, 0, 0, 0);
      Cacc = __builtin_amdgcn_mfma_f32_16x16x32_bf16(ph, vl, Cacc, 0, 0, 0);
    }
    if (c < 3){
      #pragma unroll
      for (int m = 0; m < 8; m++){
        int i = w + 8 * m;
        *(float2*)&bufA[lane * 130 + 2*i] = make_float2(ka[m], kb[m]);
      }
    }
    __syncthreads();
  }

  #pragma unroll
  for (int off = 1; off < 64; off <<= 1){
    den0 += __shfl_xor(den0, off, 64);
    den1 += __shfl_xor(den1, off, 64);
  }
  if (lane == 0){ dn[r0] = den0; dn[r0 + 1] = den1; }
  __syncthreads();
  if (w >= 4){
    #pragma unroll
    for (int r = 0; r < 4; r++) cmb[(w - 4) * 256 + lane * 4 + r] = Cacc[r];
  }
  __syncthreads();
  if (w < 4){
    #pragma unroll
    for (int r = 0; r < 4; r++){
      float cv = Cacc[r] + cmb[w * 256 + lane * 4 + r];
      int row = quad * 4 + r;
      int d = ntile * 16 + l15;
      Oh[kbase + (size_t)(i0 + row) * 512 + d] = cv / dn[row];
    }
  }
}

// ---------------- launch ----------------
extern "C" void kernel_launch(void* const* d_in, const int* in_sizes, int n_in,
                              void* d_out, int out_size, void* d_ws, size_t ws_size,
                              hipStream_t stream){
  const float* q_in = (const float*)d_in[0];
  const float* k_in = (const float*)d_in[1];
  const float* v_in = (const float*)d_in[2];
  const float* Wq_  = (const float*)d_in[3];
  const float* bq_  = (const float*)d_in[4];
  const float* Wk_  = (const float*)d_in[5];
  const float* bk_  = (const float*)d_in[6];
  const float* Wv_  = (const float*)d_in[7];
  const float* bv_  = (const float*)d_in[8];
  const float* Wo_  = (const float*)d_in[9];
  const float* bo_  = (const float*)d_in[10];
  const float* Aq_  = (const float*)d_in[11];
  const float* Ak_  = (const float*)d_in[12];
  const float* av_  = (const float*)d_in[13];

  char* ws = (char*)d_ws;
  unsigned short* W2qp = (unsigned short*)(ws + 0);
  unsigned short* W2kp = (unsigned short*)(ws + 1048576);
  float* Oh = (float*)(ws + 0);
  unsigned short* Wvp = (unsigned short*)(ws + 2097152);
  unsigned short* Wop = (unsigned short*)(ws + 3145728);
  float* b2q  = (float*)(ws + 4194304);
  float* b2k  = (float*)(ws + 4196352);
  float* av2g = (float*)(ws + 4198400);
  float* eqT  = (float*)(ws + 4198656);
  float* ekp  = (float*)(ws + 6295808);
  float* Vw   = (float*)(ws + 8392960);

  prep_all<<<dim3(1281, 2, 1), 256, 0, stream>>>(Wq_, Aq_, Wk_, Ak_, bq_, bk_, av_,
                                                 Wv_, Wo_,
                                                 W2qp, W2kp, Wvp, Wop,
                                                 b2q, b2k, av2g);

  GemmArgs ga;
  ga.g[0] = { q_in, W2qp, b2q, eqT, 1, 1 };
  ga.g[1] = { k_in, W2kp, b2k, ekp, 0, 1 };
  ga.g[2] = { v_in, Wvp,  bv_, Vw,  0, 0 };
  gemm_nk<<<dim3(16, 8, 3), 256, 0, stream>>>(ga);

  attn_kernel<<<dim3(32, 16, 1), 512, 0, stream>>>(eqT, ekp, Vw, av2g, Oh);

  GemmArgs go;
  go.g[0] = { Oh, Wop, bo_, (float*)d_out, 0, 0 };
  go.g[1] = go.g[0];
  go.g[2] = go.g[0];
  gemm_nk<<<dim3(16, 8, 1), 256, 0, stream>>>(go);
}